// Round 6
// baseline (2870.668 us; speedup 1.0000x reference)
//
#include <hip/hip_runtime.h>
#include <hip/hip_bf16.h>

#define HID 128
#define SEQ 2048
#define BATCH 64
#define NOUT 512

typedef __attribute__((ext_vector_type(8))) short bf16x8;
typedef __attribute__((ext_vector_type(4))) float f32x4;

__device__ __forceinline__ short f2bf(float f) {
    unsigned u = __float_as_uint(f);
    unsigned r = u + 0x7fffu + ((u >> 16) & 1u);   // RNE
    return (short)(r >> 16);
}

__device__ __forceinline__ float fast_sigmoid(float x) {
    return 1.0f / (1.0f + __expf(-x));
}
__device__ __forceinline__ float fast_tanh(float x) {
    return 1.0f - 2.0f / (__expf(2.0f * x) + 1.0f);
}

// ---------------------------------------------------------------------------
// GRU recurrence, pure f32, r2-PROVEN dataflow (LDS gh exchange, no cross-
// lane ops — r4/r5's mov_dpp reductions both produced O(range) errors and
// DPP is not among the HW-verified gfx950 primitives; banned this session).
//
// Ownership change vs r2 for LDS-pipe relief (the measured wall: r2 =
// 12 waves x 16 ds_read_b128 = 192 broadcast reads/step ~= 1900 cyc):
// FULL row per thread -> 384 threads = 6 waves, each wave reads h once
// (8 x b128 broadcast) => 48 wave-reads + ~14 misc LDS ops per step.
//
// r1's spill (VGPR=100, w[128] in scratch) is fixed by pinning the
// allocator budget: amdgpu_waves_per_eu(1,2) => 256-VGPR cap. r3 proved
// the attribute steers allocation. Tell: VGPR_Count must be >128.
// ---------------------------------------------------------------------------
__global__ __launch_bounds__(384)
__attribute__((amdgpu_waves_per_eu(1, 2)))
void gru_seq(
    const float* __restrict__ latent,   // [BATCH][HID]
    const float* __restrict__ W_hh,     // [3*HID][HID]
    const float* __restrict__ b_ih,     // [3*HID]
    const float* __restrict__ b_hh,     // [3*HID]
    __hip_bfloat16* __restrict__ hs)    // [BATCH][SEQ][HID]  (bf16)
{
    const int b = blockIdx.x;
    const int j = threadIdx.x;          // 0..383 : full W_hh row j

    __shared__ __align__(16) float h_s[HID];   // 512 B
    __shared__ float gh_s[3 * HID];            // 1536 B

    // Full row j of W_hh in VGPRs (128 regs as 32 float4s).
    float4 w4[32];
    {
        const float4* wrow = (const float4*)(W_hh + j * HID);
        #pragma unroll
        for (int c = 0; c < 32; c++) w4[c] = wrow[c];
    }
    const float bhh = b_hh[j];

    float bir = 0.f, biz = 0.f, bin = 0.f, h_old = 0.f;
    if (j < HID) {
        bir = b_ih[j];
        biz = b_ih[HID + j];
        bin = b_ih[2 * HID + j];
        h_old = latent[b * HID + j];
        h_s[j] = h_old;
    }
    __syncthreads();

    __hip_bfloat16* out_row = hs + (size_t)b * SEQ * HID;

    for (int t = 0; t < SEQ; t++) {
        // full dot: gh[j] = sum_k h[k] * W_hh[j][k]   (4 independent accums)
        float a0 = 0.f, a1 = 0.f, a2 = 0.f, a3 = 0.f;
        const float4* hp = (const float4*)h_s;
        #pragma unroll
        for (int c = 0; c < 32; c++) {
            float4 hv = hp[c];               // 64-lane same-addr broadcast
            float4 wv = w4[c];
            a0 = fmaf(hv.x, wv.x, a0);
            a1 = fmaf(hv.y, wv.y, a1);
            a2 = fmaf(hv.z, wv.z, a2);
            a3 = fmaf(hv.w, wv.w, a3);
        }
        gh_s[j] = (a0 + a1) + (a2 + a3) + bhh;
        __syncthreads();

        if (j < HID) {
            float r  = fast_sigmoid(bir + gh_s[j]);
            float z  = fast_sigmoid(biz + gh_s[HID + j]);
            float n  = fast_tanh(bin + r * gh_s[2 * HID + j]);
            h_old = (1.0f - z) * n + z * h_old;    // h stays in register
            h_s[j] = h_old;
            out_row[t * HID + j] =
                __builtin_bit_cast(__hip_bfloat16, (unsigned short)f2bf(h_old));
        }
        __syncthreads();
    }
}

// ---------------------------------------------------------------------------
// Repack fc_W (f32 [512][128]) into bf16 MFMA B-fragment order (r2-proven).
// ---------------------------------------------------------------------------
__global__ void wprep(const float* __restrict__ fc_W,
                      __hip_bfloat16* __restrict__ wfrag)
{
    int t = blockIdx.x * 256 + threadIdx.x;      // 0..65535
    int j    = t & 7;
    int lane = (t >> 3) & 63;
    int q    = (t >> 9) & 3;
    int ct   = t >> 11;
    int n = ct * 16 + (lane & 15);
    int k = q * 32 + (lane >> 4) * 8 + j;
    unsigned short v = (unsigned short)f2bf(fc_W[n * HID + k]);
    wfrag[t] = __builtin_bit_cast(__hip_bfloat16, v);
}

// ---------------------------------------------------------------------------
// Projection (r2-proven): out = hs @ fc_W.T + fc_b via bf16 MFMA 16x16x32.
// ---------------------------------------------------------------------------
__global__ __launch_bounds__(256) void proj_mfma(
    const __hip_bfloat16* __restrict__ hsb,    // [M][128] bf16
    const __hip_bfloat16* __restrict__ wfrag,  // fragment-ordered [32][4][64][8]
    const float* __restrict__ fc_b,            // [512]
    float* __restrict__ out)                   // [M][512] f32
{
    const int lane = threadIdx.x & 63;
    const int wave = threadIdx.x >> 6;
    const int m    = lane & 15;
    const int quad = lane >> 4;

    const long r0 = ((long)blockIdx.x * 4 + wave) * 32;

    bf16x8 afrag[2][4];
    #pragma unroll
    for (int rt = 0; rt < 2; rt++) {
        #pragma unroll
        for (int q = 0; q < 4; q++) {
            const __hip_bfloat16* p =
                hsb + (r0 + rt * 16 + m) * HID + q * 32 + quad * 8;
            afrag[rt][q] = *(const bf16x8*)p;   // 16B aligned
        }
    }

    for (int ct = 0; ct < 32; ct++) {
        f32x4 acc0 = {0.f, 0.f, 0.f, 0.f};
        f32x4 acc1 = {0.f, 0.f, 0.f, 0.f};
        #pragma unroll
        for (int q = 0; q < 4; q++) {
            bf16x8 bb = *(const bf16x8*)(wfrag + ((ct * 4 + q) * 64 + lane) * 8);
            acc0 = __builtin_amdgcn_mfma_f32_16x16x32_bf16(afrag[0][q], bb, acc0, 0, 0, 0);
            acc1 = __builtin_amdgcn_mfma_f32_16x16x32_bf16(afrag[1][q], bb, acc1, 0, 0, 0);
        }
        const int col = ct * 16 + m;
        const float bias = fc_b[col];
        #pragma unroll
        for (int reg = 0; reg < 4; reg++) {
            const int row_in = quad * 4 + reg;
            out[(r0 + row_in) * NOUT + col]      = acc0[reg] + bias;
            out[(r0 + 16 + row_in) * NOUT + col] = acc1[reg] + bias;
        }
    }
}

extern "C" void kernel_launch(void* const* d_in, const int* in_sizes, int n_in,
                              void* d_out, int out_size, void* d_ws, size_t ws_size,
                              hipStream_t stream) {
    const float* latent = (const float*)d_in[0];   // (64,128)
    const float* W_hh   = (const float*)d_in[1];   // (384,128)
    const float* b_ih   = (const float*)d_in[2];   // (384,)
    const float* b_hh   = (const float*)d_in[3];   // (384,)
    const float* fc_W   = (const float*)d_in[4];   // (512,128)
    const float* fc_b   = (const float*)d_in[5];   // (512,)
    float* out = (float*)d_out;                    // (64,2048,512)

    __hip_bfloat16* hsb   = (__hip_bfloat16*)d_ws;                   // 33.5 MB
    __hip_bfloat16* wfrag = (__hip_bfloat16*)((char*)d_ws + (size_t)BATCH * SEQ * HID * 2);

    wprep<<<256, 256, 0, stream>>>(fc_W, wfrag);
    gru_seq<<<BATCH, 384, 0, stream>>>(latent, W_hh, b_ih, b_hh, hsb);

    const int M = BATCH * SEQ;                     // 131072
    proj_mfma<<<M / 128, 256, 0, stream>>>(hsb, wfrag, fc_b, out);
}